// Round 2
// baseline (1011.498 us; speedup 1.0000x reference)
//
#include <hip/hip_runtime.h>

// mean over axis 1: mailbox[50000][32][128] f32 -> out[50000][128] f32.
// 819.2 MB read + 25.6 MB write, zero reuse -> pure HBM-bound streaming.
//
// Structure (R2): block = 256 threads = 2 nodes. Each thread sums 8 rows
// (one row-quarter) of one column-float4: 8 loads off ONE base address with
// immediate offsets k*512B (<=3584 < 4096 signed-13b limit) -> minimal VALU,
// ~45 VGPRs -> 8 waves/SIMD occupancy. Partials combined via 4 KB LDS.
// Per load instruction a wave touches two contiguous 512 B segments -> coalesced.

constexpr int N_NODES = 50000;
constexpr int MAX_DEG = 32;
constexpr int F4      = 32;   // 128 floats = 32 float4 per row
constexpr int NODES_PER_BLOCK = 2;

__global__ __launch_bounds__(256, 8) void mean_agg_kernel(
    const float4* __restrict__ in, float4* __restrict__ out) {
    __shared__ float4 part[256];

    const int t  = threadIdx.x;
    const int nb = blockIdx.x * NODES_PER_BLOCK;
    const int ln = t >> 7;        // node within block (0..1)
    const int l  = t & 127;
    const int rq = l >> 5;        // row-quarter (0..3), rows rq*8 .. rq*8+7
    const int j  = l & 31;        // column float4 (0..31)

    const float4* p = in + ((size_t)(nb + ln) * MAX_DEG + rq * 8) * F4 + j;

    float4 a = make_float4(0.f, 0.f, 0.f, 0.f);
    float4 b = make_float4(0.f, 0.f, 0.f, 0.f);
#pragma unroll
    for (int k = 0; k < 8; k += 2) {
        float4 v0 = p[(size_t)k * F4];
        float4 v1 = p[(size_t)(k + 1) * F4];
        a.x += v0.x; a.y += v0.y; a.z += v0.z; a.w += v0.w;
        b.x += v1.x; b.y += v1.y; b.z += v1.z; b.w += v1.w;
    }
    a.x += b.x; a.y += b.y; a.z += b.z; a.w += b.w;
    part[t] = a;
    __syncthreads();

    if (t < 64) {
        const int base = (t >> 5) * 128 + (t & 31);  // ln'*128 + j
        float4 s0 = part[base];
        float4 s1 = part[base + 32];
        float4 s2 = part[base + 64];
        float4 s3 = part[base + 96];
        float4 r;
        const float s = 1.0f / MAX_DEG;
        r.x = (s0.x + s1.x + s2.x + s3.x) * s;
        r.y = (s0.y + s1.y + s2.y + s3.y) * s;
        r.z = (s0.z + s1.z + s2.z + s3.z) * s;
        r.w = (s0.w + s1.w + s2.w + s3.w) * s;
        out[(size_t)nb * F4 + t] = r;   // 64 threads x 16B = 1 KB contiguous
    }
}

extern "C" void kernel_launch(void* const* d_in, const int* in_sizes, int n_in,
                              void* d_out, int out_size, void* d_ws, size_t ws_size,
                              hipStream_t stream) {
    const float4* in = (const float4*)d_in[0];
    float4* out = (float4*)d_out;
    const int grid = N_NODES / NODES_PER_BLOCK;   // 25000 blocks
    mean_agg_kernel<<<grid, 256, 0, stream>>>(in, out);
}